// Round 7
// baseline (593.387 us; speedup 1.0000x reference)
//
#include <hip/hip_runtime.h>
#include <hip/hip_bf16.h>

// GCN layer: out = spmm(adj, x @ W) + bias
// Inputs: x[50000,128] f32, weight[128,128] f32, bias[128] f32,
//         edge_vals[625000] f32, edge_rows[625000] i32, edge_cols[625000] i32
// Output: out[50000,128] f32
//
// Round 7 pipeline (4 dispatches):
//   initw : wt = bf16(w^T); fine-bucket allocators
//   bin   : LDS-staged counting sort of 8-B records into 782 buckets of
//           64 rows each (segment-flushed; ~2x line amplification vs 8x
//           for the naive random scatter)
//   gemm  : support = bf16(x @ W) via MFMA
//   bspmm : block per 64-row window; wave-uniform record loop, coalesced
//           256-B support gathers, LDS f32 tile accumulation via ds_add
//           (no row sorting, no output atomics), coalesced writes + bias.

#define F_DIM 128

#define NFB 782                 // fine buckets: row >> 6 (64 rows each)
#define NFB_PAD 784
#define SLAB_F 1024             // records per bucket (mean 799, +8 sigma)

#define BIN_T 256
#define BIN_EPT 16
#define BIN_CHUNK (BIN_T * BIN_EPT)     // 4096 edges per block

#define SPMM_T 512

typedef short bf16x8 __attribute__((ext_vector_type(8)));
typedef float f32x4 __attribute__((ext_vector_type(4)));

__device__ __forceinline__ unsigned short f2bf(float f) {
    unsigned int u = __float_as_uint(f);
    u += 0x7FFFu + ((u >> 16) & 1u);   // round-to-nearest-even
    return (unsigned short)(u >> 16);
}

// ---- initw: wt[n][k] = bf16(w[k][n]); bucket_cur[b] = b*SLAB_F ----------
__global__ void __launch_bounds__(256)
initw_kernel(const float* __restrict__ w, unsigned short* __restrict__ wt,
             int* __restrict__ bucket_cur) {
    if (blockIdx.x == 64) {
        for (int i = threadIdx.x; i < NFB; i += 256)
            bucket_cur[i] = i * SLAB_F;
        return;
    }
    int idx = blockIdx.x * 256 + threadIdx.x;
    int n = idx >> 7, k = idx & 127;
    wt[n * F_DIM + k] = f2bf(w[k * F_DIM + n]);
}

// ---- bin: stage BIN_CHUNK edges, counting-sort by 64-row bucket, flush ---
__global__ void __launch_bounds__(BIN_T)
bin_kernel(const int* __restrict__ rows, const int* __restrict__ cols,
           const float* __restrict__ vals, int* __restrict__ bucket_cur,
           uint2* __restrict__ ebin, int n_edges) {
    __shared__ int lcnt[NFB_PAD];          // counts, then running position
    __shared__ int lbase[NFB_PAD];         // local exclusive prefix
    __shared__ int garr[NFB_PAD];          // reserved global base
    __shared__ int part[BIN_T];            // scan workspace
    __shared__ uint2 srec[BIN_CHUNK];      // bucket-sorted records (32 KB)
    __shared__ unsigned short sb[BIN_CHUNK];

    const int t = threadIdx.x;
    const int base = blockIdx.x * BIN_CHUNK;

    for (int i = t; i < NFB_PAD; i += BIN_T) lcnt[i] = 0;
    __syncthreads();

    unsigned int mykey[BIN_EPT];
    float myval[BIN_EPT];
    bool myok[BIN_EPT];
#pragma unroll
    for (int j = 0; j < BIN_EPT; j++) {
        int e = base + j * BIN_T + t;
        myok[j] = (e < n_edges);
        if (myok[j]) {
            int r = rows[e];
            int c = cols[e];
            myval[j] = vals[e];
            mykey[j] = ((unsigned)r << 16) | (unsigned)c;
            atomicAdd(&lcnt[r >> 6], 1);
        }
    }
    __syncthreads();

    // exclusive scan over NFB buckets: 256 threads x 4 buckets each
    {
        const int b0 = t * 4;
        int s4 = 0;
#pragma unroll
        for (int j = 0; j < 4; j++)
            if (b0 + j < NFB_PAD) s4 += lcnt[b0 + j];
        part[t] = s4;
        __syncthreads();
        for (int d = 1; d < BIN_T; d <<= 1) {
            int u = (t >= d) ? part[t - d] : 0;
            __syncthreads();
            part[t] += u;
            __syncthreads();
        }
        int run = part[t] - s4;   // exclusive prefix of this thread's chunk
#pragma unroll
        for (int j = 0; j < 4; j++) {
            int b = b0 + j;
            if (b < NFB_PAD) {
                lbase[b] = run;
                run += lcnt[b];
            }
        }
    }
    __syncthreads();
    // reserve global slab space; reset lcnt to running placement base
    for (int b = t; b < NFB; b += BIN_T) {
        int c = lcnt[b];
        if (c > 0) garr[b] = atomicAdd(&bucket_cur[b], c);
        lcnt[b] = lbase[b];
    }
    __syncthreads();

#pragma unroll
    for (int j = 0; j < BIN_EPT; j++) {
        if (myok[j]) {
            int b = (int)(mykey[j] >> 22);        // row >> 6
            int p = atomicAdd(&lcnt[b], 1);
            srec[p] = make_uint2(mykey[j], __float_as_uint(myval[j]));
            sb[p] = (unsigned short)b;
        }
    }
    __syncthreads();

    const int m = min(BIN_CHUNK, n_edges - base);
    for (int i = t; i < m; i += BIN_T) {
        int b = sb[i];
        int dst = garr[b] + (i - lbase[b]);
        if (dst < (b + 1) * SLAB_F) ebin[dst] = srec[i];  // overflow guard
    }
}

// ---- GEMM: support_bf16 = bf16(x @ W) via MFMA ---------------------------
__global__ void __launch_bounds__(256)
gemm_mfma_kernel(const float* __restrict__ x, const unsigned short* __restrict__ wt,
                 unsigned short* __restrict__ support) {
    const int tid = threadIdx.x;
    const int wid = tid >> 6;
    const int lane = tid & 63;
    const int l15 = lane & 15;
    const int lhi = lane >> 4;           // 0..3

    const int m0 = (blockIdx.x >> 1) * 16;           // 3125*16 = 50000 exact
    const int n0 = (blockIdx.x & 1) * 64 + wid * 16;

    const float* xrow = x + (size_t)(m0 + l15) * F_DIM + lhi * 8;
    const unsigned short* wrow = wt + (size_t)(n0 + l15) * F_DIM + lhi * 8;

    f32x4 acc = {0.f, 0.f, 0.f, 0.f};
#pragma unroll
    for (int k0 = 0; k0 < F_DIM; k0 += 32) {
        float4 xa = *reinterpret_cast<const float4*>(xrow + k0);
        float4 xb = *reinterpret_cast<const float4*>(xrow + k0 + 4);
        bf16x8 a, b;
        a[0] = (short)f2bf(xa.x); a[1] = (short)f2bf(xa.y);
        a[2] = (short)f2bf(xa.z); a[3] = (short)f2bf(xa.w);
        a[4] = (short)f2bf(xb.x); a[5] = (short)f2bf(xb.y);
        a[6] = (short)f2bf(xb.z); a[7] = (short)f2bf(xb.w);
        b = *reinterpret_cast<const bf16x8*>(wrow + k0);
        acc = __builtin_amdgcn_mfma_f32_16x16x32_bf16(a, b, acc, 0, 0, 0);
    }

    unsigned short* sp = support + (size_t)(m0 + 4 * lhi) * F_DIM + n0 + l15;
#pragma unroll
    for (int i = 0; i < 4; i++)
        sp[(size_t)i * F_DIM] = f2bf(acc[i]);
}

// ---- bspmm: block per 64-row window; LDS f32 tile + ds_add accumulation --
__global__ void __launch_bounds__(SPMM_T)
bspmm_kernel(const unsigned short* __restrict__ support,
             const uint2* __restrict__ ebin, const int* __restrict__ bucket_cur,
             const float* __restrict__ bias, float* __restrict__ out,
             int n_nodes) {
    __shared__ float tile[64 * F_DIM];   // 32 KB

    const int blk = blockIdx.x;
    const int w0 = blk * 64;
    const int s = blk * SLAB_F;
    const int e = min(bucket_cur[blk], (blk + 1) * SLAB_F);

    const int t = threadIdx.x;
    const int w = t >> 6;
    const int lane = t & 63;

    // zero the tile
    float4* tile4 = reinterpret_cast<float4*>(tile);
    for (int i = t; i < 64 * F_DIM / 4; i += SPMM_T)
        tile4[i] = make_float4(0.f, 0.f, 0.f, 0.f);
    __syncthreads();

    // record loop: wave-uniform record, coalesced gather, LDS atomic adds.
    // Iterations independent -> loads pipeline across vmcnt.
    for (int i = s + w; i < e; i += 8) {
        uint2 rec = ebin[i];                       // uniform across the wave
        int r = (int)(rec.x >> 16) - w0;           // 0..63
        int col = (int)(rec.x & 0xffffu);
        float v = __uint_as_float(rec.y);
        unsigned sv = *reinterpret_cast<const unsigned*>(
            support + (size_t)col * F_DIM + lane * 2);
        atomicAdd(&tile[r * F_DIM + lane * 2],     v * __uint_as_float(sv << 16));
        atomicAdd(&tile[r * F_DIM + lane * 2 + 1], v * __uint_as_float(sv & 0xFFFF0000u));
    }
    __syncthreads();

    // epilogue: out[row] = tile[row] + bias (coalesced float2 stores)
    const float2 bb = *reinterpret_cast<const float2*>(bias + lane * 2);
    for (int r = w; r < 64; r += 8) {
        int row = w0 + r;
        if (row < n_nodes) {
            float2 o;
            o.x = tile[r * F_DIM + lane * 2] + bb.x;
            o.y = tile[r * F_DIM + lane * 2 + 1] + bb.y;
            *reinterpret_cast<float2*>(out + (size_t)row * F_DIM + lane * 2) = o;
        }
    }
}

extern "C" void kernel_launch(void* const* d_in, const int* in_sizes, int n_in,
                              void* d_out, int out_size, void* d_ws, size_t ws_size,
                              hipStream_t stream) {
    const float* x      = (const float*)d_in[0];
    const float* weight = (const float*)d_in[1];
    const float* bias   = (const float*)d_in[2];
    const float* evals  = (const float*)d_in[3];
    const int*   erows  = (const int*)d_in[4];
    const int*   ecols  = (const int*)d_in[5];
    float* out = (float*)d_out;

    const int n_nodes = in_sizes[0] / F_DIM;   // 50000
    const int n_edges = in_sizes[3];           // 625000

    // Workspace layout (~19.3 MB)
    unsigned short* support = (unsigned short*)d_ws;                  // n_nodes*128 bf16
    unsigned short* wt      = support + (size_t)n_nodes * F_DIM;      // 128*128 bf16
    int* bucket_cur = (int*)(wt + F_DIM * F_DIM);                     // NFB
    uintptr_t ep = (uintptr_t)(bucket_cur + NFB);
    ep = (ep + 15) & ~(uintptr_t)15;
    uint2* ebin = (uint2*)ep;                                         // NFB*SLAB_F*8 B

    // 1) wt = bf16(w^T); bucket allocators
    initw_kernel<<<65, 256, 0, stream>>>(weight, wt, bucket_cur);

    // 2) bin edges into 64-row buckets (segment-flushed counting sort)
    int bin_blocks = (n_edges + BIN_CHUNK - 1) / BIN_CHUNK;           // 153
    bin_kernel<<<bin_blocks, BIN_T, 0, stream>>>(erows, ecols, evals,
                                                 bucket_cur, ebin, n_edges);

    // 3) support = bf16(x @ W) via MFMA
    gemm_mfma_kernel<<<(n_nodes / 16) * 2, 256, 0, stream>>>(x, wt, support);

    // 4) windowed pull-spmm: LDS tile + ds_add, no filter waste
    bspmm_kernel<<<NFB, SPMM_T, 0, stream>>>(support, ebin, bucket_cur,
                                             bias, out, n_nodes);
}

// Round 8
// 591.852 us; speedup vs baseline: 1.0026x; 1.0026x over previous
//
#include <hip/hip_runtime.h>
#include <hip/hip_bf16.h>

// GCN layer: out = spmm(adj, x @ W) + bias
// Inputs: x[50000,128] f32, weight[128,128] f32, bias[128] f32,
//         edge_vals[625000] f32, edge_rows[625000] i32, edge_cols[625000] i32
// Output: out[50000,128] f32
//
// Round 8 pipeline (4 dispatches):
//   initw : wt = bf16(w^T); fine-bucket allocators
//   bin   : LDS-staged counting sort of 8-B records into 782 buckets of
//           64 rows each (segment-flushed writes)
//   gemm  : support = bf16(x @ W) via MFMA
//   bspmm : block per 64-row window; wave-uniform record loop (4x unrolled),
//           coalesced 256-B support gathers, LDS f32 tile accumulation via
//           unsafeAtomicAdd -> hardware ds_add_f32 (round-7 lesson: plain
//           atomicAdd on LDS floats compiles to a CAS loop -> 535 us).

#define F_DIM 128

#define NFB 782                 // fine buckets: row >> 6 (64 rows each)
#define NFB_PAD 784
#define SLAB_F 1024             // records per bucket (mean 799, +8 sigma)

#define BIN_T 256
#define BIN_EPT 16
#define BIN_CHUNK (BIN_T * BIN_EPT)     // 4096 edges per block

#define SPMM_T 512

typedef short bf16x8 __attribute__((ext_vector_type(8)));
typedef float f32x4 __attribute__((ext_vector_type(4)));

__device__ __forceinline__ unsigned short f2bf(float f) {
    unsigned int u = __float_as_uint(f);
    u += 0x7FFFu + ((u >> 16) & 1u);   // round-to-nearest-even
    return (unsigned short)(u >> 16);
}

// ---- initw: wt[n][k] = bf16(w[k][n]); bucket_cur[b] = b*SLAB_F ----------
__global__ void __launch_bounds__(256)
initw_kernel(const float* __restrict__ w, unsigned short* __restrict__ wt,
             int* __restrict__ bucket_cur) {
    if (blockIdx.x == 64) {
        for (int i = threadIdx.x; i < NFB; i += 256)
            bucket_cur[i] = i * SLAB_F;
        return;
    }
    int idx = blockIdx.x * 256 + threadIdx.x;
    int n = idx >> 7, k = idx & 127;
    wt[n * F_DIM + k] = f2bf(w[k * F_DIM + n]);
}

// ---- bin: stage BIN_CHUNK edges, counting-sort by 64-row bucket, flush ---
__global__ void __launch_bounds__(BIN_T)
bin_kernel(const int* __restrict__ rows, const int* __restrict__ cols,
           const float* __restrict__ vals, int* __restrict__ bucket_cur,
           uint2* __restrict__ ebin, int n_edges) {
    __shared__ int lcnt[NFB_PAD];          // counts, then running position
    __shared__ int lbase[NFB_PAD];         // local exclusive prefix
    __shared__ int garr[NFB_PAD];          // reserved global base
    __shared__ int part[BIN_T];            // scan workspace
    __shared__ uint2 srec[BIN_CHUNK];      // bucket-sorted records (32 KB)
    __shared__ unsigned short sb[BIN_CHUNK];

    const int t = threadIdx.x;
    const int base = blockIdx.x * BIN_CHUNK;

    for (int i = t; i < NFB_PAD; i += BIN_T) lcnt[i] = 0;
    __syncthreads();

    unsigned int mykey[BIN_EPT];
    float myval[BIN_EPT];
    bool myok[BIN_EPT];
#pragma unroll
    for (int j = 0; j < BIN_EPT; j++) {
        int e = base + j * BIN_T + t;
        myok[j] = (e < n_edges);
        if (myok[j]) {
            int r = rows[e];
            int c = cols[e];
            myval[j] = vals[e];
            mykey[j] = ((unsigned)r << 16) | (unsigned)c;
            atomicAdd(&lcnt[r >> 6], 1);
        }
    }
    __syncthreads();

    // exclusive scan over NFB buckets: 256 threads x 4 buckets each
    {
        const int b0 = t * 4;
        int s4 = 0;
#pragma unroll
        for (int j = 0; j < 4; j++)
            if (b0 + j < NFB_PAD) s4 += lcnt[b0 + j];
        part[t] = s4;
        __syncthreads();
        for (int d = 1; d < BIN_T; d <<= 1) {
            int u = (t >= d) ? part[t - d] : 0;
            __syncthreads();
            part[t] += u;
            __syncthreads();
        }
        int run = part[t] - s4;   // exclusive prefix of this thread's chunk
#pragma unroll
        for (int j = 0; j < 4; j++) {
            int b = b0 + j;
            if (b < NFB_PAD) {
                lbase[b] = run;
                run += lcnt[b];
            }
        }
    }
    __syncthreads();
    // reserve global slab space; reset lcnt to running placement base
    for (int b = t; b < NFB; b += BIN_T) {
        int c = lcnt[b];
        if (c > 0) garr[b] = atomicAdd(&bucket_cur[b], c);
        lcnt[b] = lbase[b];
    }
    __syncthreads();

#pragma unroll
    for (int j = 0; j < BIN_EPT; j++) {
        if (myok[j]) {
            int b = (int)(mykey[j] >> 22);        // row >> 6
            int p = atomicAdd(&lcnt[b], 1);
            srec[p] = make_uint2(mykey[j], __float_as_uint(myval[j]));
            sb[p] = (unsigned short)b;
        }
    }
    __syncthreads();

    const int m = min(BIN_CHUNK, n_edges - base);
    for (int i = t; i < m; i += BIN_T) {
        int b = sb[i];
        int dst = garr[b] + (i - lbase[b]);
        if (dst < (b + 1) * SLAB_F) ebin[dst] = srec[i];  // overflow guard
    }
}

// ---- GEMM: support_bf16 = bf16(x @ W) via MFMA ---------------------------
__global__ void __launch_bounds__(256)
gemm_mfma_kernel(const float* __restrict__ x, const unsigned short* __restrict__ wt,
                 unsigned short* __restrict__ support) {
    const int tid = threadIdx.x;
    const int wid = tid >> 6;
    const int lane = tid & 63;
    const int l15 = lane & 15;
    const int lhi = lane >> 4;           // 0..3

    const int m0 = (blockIdx.x >> 1) * 16;           // 3125*16 = 50000 exact
    const int n0 = (blockIdx.x & 1) * 64 + wid * 16;

    const float* xrow = x + (size_t)(m0 + l15) * F_DIM + lhi * 8;
    const unsigned short* wrow = wt + (size_t)(n0 + l15) * F_DIM + lhi * 8;

    f32x4 acc = {0.f, 0.f, 0.f, 0.f};
#pragma unroll
    for (int k0 = 0; k0 < F_DIM; k0 += 32) {
        float4 xa = *reinterpret_cast<const float4*>(xrow + k0);
        float4 xb = *reinterpret_cast<const float4*>(xrow + k0 + 4);
        bf16x8 a, b;
        a[0] = (short)f2bf(xa.x); a[1] = (short)f2bf(xa.y);
        a[2] = (short)f2bf(xa.z); a[3] = (short)f2bf(xa.w);
        a[4] = (short)f2bf(xb.x); a[5] = (short)f2bf(xb.y);
        a[6] = (short)f2bf(xb.z); a[7] = (short)f2bf(xb.w);
        b = *reinterpret_cast<const bf16x8*>(wrow + k0);
        acc = __builtin_amdgcn_mfma_f32_16x16x32_bf16(a, b, acc, 0, 0, 0);
    }

    unsigned short* sp = support + (size_t)(m0 + 4 * lhi) * F_DIM + n0 + l15;
#pragma unroll
    for (int i = 0; i < 4; i++)
        sp[(size_t)i * F_DIM] = f2bf(acc[i]);
}

// ---- bspmm: block per 64-row window; LDS f32 tile + hw ds_add_f32 --------
__global__ void __launch_bounds__(SPMM_T)
bspmm_kernel(const unsigned short* __restrict__ support,
             const uint2* __restrict__ ebin, const int* __restrict__ bucket_cur,
             const float* __restrict__ bias, float* __restrict__ out,
             int n_nodes) {
    __shared__ float tile[64 * F_DIM];   // 32 KB

    const int blk = blockIdx.x;
    const int w0 = blk * 64;
    const int s = blk * SLAB_F;
    const int e = min(bucket_cur[blk], (blk + 1) * SLAB_F);

    const int t = threadIdx.x;
    const int w = t >> 6;
    const int lane = t & 63;

    // zero the tile
    float4* tile4 = reinterpret_cast<float4*>(tile);
    for (int i = t; i < 64 * F_DIM / 4; i += SPMM_T)
        tile4[i] = make_float4(0.f, 0.f, 0.f, 0.f);
    __syncthreads();

    const unsigned foff = lane * 2u;

    // record loop, 4x unrolled: 4 independent uniform record loads, then
    // 4 independent 256-B gathers, then 8 hw ds_add_f32.
    int i = s + w;
#pragma unroll 1
    for (; i + 24 < e; i += 32) {
        uint2 r0 = ebin[i];
        uint2 r1 = ebin[i + 8];
        uint2 r2 = ebin[i + 16];
        uint2 r3 = ebin[i + 24];
        unsigned s0 = *reinterpret_cast<const unsigned*>(
            support + (size_t)(r0.x & 0xffffu) * F_DIM + foff);
        unsigned s1 = *reinterpret_cast<const unsigned*>(
            support + (size_t)(r1.x & 0xffffu) * F_DIM + foff);
        unsigned s2 = *reinterpret_cast<const unsigned*>(
            support + (size_t)(r2.x & 0xffffu) * F_DIM + foff);
        unsigned s3 = *reinterpret_cast<const unsigned*>(
            support + (size_t)(r3.x & 0xffffu) * F_DIM + foff);
        float* t0 = &tile[((r0.x >> 16) - w0) * F_DIM + foff];
        float* t1 = &tile[((r1.x >> 16) - w0) * F_DIM + foff];
        float* t2 = &tile[((r2.x >> 16) - w0) * F_DIM + foff];
        float* t3 = &tile[((r3.x >> 16) - w0) * F_DIM + foff];
        float v0 = __uint_as_float(r0.y), v1 = __uint_as_float(r1.y);
        float v2 = __uint_as_float(r2.y), v3 = __uint_as_float(r3.y);
        unsafeAtomicAdd(t0,     v0 * __uint_as_float(s0 << 16));
        unsafeAtomicAdd(t0 + 1, v0 * __uint_as_float(s0 & 0xFFFF0000u));
        unsafeAtomicAdd(t1,     v1 * __uint_as_float(s1 << 16));
        unsafeAtomicAdd(t1 + 1, v1 * __uint_as_float(s1 & 0xFFFF0000u));
        unsafeAtomicAdd(t2,     v2 * __uint_as_float(s2 << 16));
        unsafeAtomicAdd(t2 + 1, v2 * __uint_as_float(s2 & 0xFFFF0000u));
        unsafeAtomicAdd(t3,     v3 * __uint_as_float(s3 << 16));
        unsafeAtomicAdd(t3 + 1, v3 * __uint_as_float(s3 & 0xFFFF0000u));
    }
#pragma unroll 1
    for (; i < e; i += 8) {
        uint2 rec = ebin[i];
        int col = (int)(rec.x & 0xffffu);
        float v = __uint_as_float(rec.y);
        unsigned sv = *reinterpret_cast<const unsigned*>(
            support + (size_t)col * F_DIM + foff);
        float* tp = &tile[((rec.x >> 16) - w0) * F_DIM + foff];
        unsafeAtomicAdd(tp,     v * __uint_as_float(sv << 16));
        unsafeAtomicAdd(tp + 1, v * __uint_as_float(sv & 0xFFFF0000u));
    }
    __syncthreads();

    // epilogue: out[row] = tile[row] + bias (coalesced float2 stores)
    const float2 bb = *reinterpret_cast<const float2*>(bias + foff);
    for (int r = w; r < 64; r += 8) {
        int row = w0 + r;
        if (row < n_nodes) {
            float2 o;
            o.x = tile[r * F_DIM + foff] + bb.x;
            o.y = tile[r * F_DIM + foff + 1] + bb.y;
            *reinterpret_cast<float2*>(out + (size_t)row * F_DIM + foff) = o;
        }
    }
}

extern "C" void kernel_launch(void* const* d_in, const int* in_sizes, int n_in,
                              void* d_out, int out_size, void* d_ws, size_t ws_size,
                              hipStream_t stream) {
    const float* x      = (const float*)d_in[0];
    const float* weight = (const float*)d_in[1];
    const float* bias   = (const float*)d_in[2];
    const float* evals  = (const float*)d_in[3];
    const int*   erows  = (const int*)d_in[4];
    const int*   ecols  = (const int*)d_in[5];
    float* out = (float*)d_out;

    const int n_nodes = in_sizes[0] / F_DIM;   // 50000
    const int n_edges = in_sizes[3];           // 625000

    // Workspace layout (~19.3 MB)
    unsigned short* support = (unsigned short*)d_ws;                  // n_nodes*128 bf16
    unsigned short* wt      = support + (size_t)n_nodes * F_DIM;      // 128*128 bf16
    int* bucket_cur = (int*)(wt + F_DIM * F_DIM);                     // NFB
    uintptr_t ep = (uintptr_t)(bucket_cur + NFB);
    ep = (ep + 15) & ~(uintptr_t)15;
    uint2* ebin = (uint2*)ep;                                         // NFB*SLAB_F*8 B

    // 1) wt = bf16(w^T); bucket allocators
    initw_kernel<<<65, 256, 0, stream>>>(weight, wt, bucket_cur);

    // 2) bin edges into 64-row buckets (segment-flushed counting sort)
    int bin_blocks = (n_edges + BIN_CHUNK - 1) / BIN_CHUNK;           // 153
    bin_kernel<<<bin_blocks, BIN_T, 0, stream>>>(erows, ecols, evals,
                                                 bucket_cur, ebin, n_edges);

    // 3) support = bf16(x @ W) via MFMA
    gemm_mfma_kernel<<<(n_nodes / 16) * 2, 256, 0, stream>>>(x, wt, support);

    // 4) windowed pull-spmm: LDS tile + hw ds_add, no filter waste
    bspmm_kernel<<<NFB, SPMM_T, 0, stream>>>(support, ebin, bucket_cur,
                                             bias, out, n_nodes);
}

// Round 9
// 190.340 us; speedup vs baseline: 3.1175x; 3.1094x over previous
//
#include <hip/hip_runtime.h>
#include <hip/hip_bf16.h>

// GCN layer: out = spmm(adj, x @ W) + bias
// Inputs: x[50000,128] f32, weight[128,128] f32, bias[128] f32,
//         edge_vals[625000] f32, edge_rows[625000] i32, edge_cols[625000] i32
// Output: out[50000,128] f32
//
// Round 9 pipeline (4 dispatches):
//   initw : wt = bf16(w^T); fine-bucket allocators
//   bin   : LDS-staged counting sort of 8-B records into 782 buckets of
//           64 rows each (segment-flushed writes)  [unchanged, proven]
//   gemm  : support = bf16(x @ W) via MFMA          [unchanged]
//   bspmm : block (4 waves) per bucket; wave owns 16 rows + private LDS
//           strip; uniform record scan, uniform ownership branch, plain
//           (non-atomic) LDS RMW.  Round-7/8 lesson: float atomicAdd /
//           unsafeAtomicAdd on generic __shared__ pointers lowers to the
//           flat path (SQ_LDS_BANK_CONFLICT==0, 535us) -> NO float atomics.

#define F_DIM 128

#define NFB 782                 // buckets: row >> 6 (64 rows each)
#define NFB_PAD 784
#define SLAB_F 1024             // records per bucket (mean 799, +8 sigma)

#define BIN_T 256
#define BIN_EPT 16
#define BIN_CHUNK (BIN_T * BIN_EPT)     // 4096 edges per block

typedef short bf16x8 __attribute__((ext_vector_type(8)));
typedef float f32x4 __attribute__((ext_vector_type(4)));

__device__ __forceinline__ unsigned short f2bf(float f) {
    unsigned int u = __float_as_uint(f);
    u += 0x7FFFu + ((u >> 16) & 1u);   // round-to-nearest-even
    return (unsigned short)(u >> 16);
}

// ---- initw: wt[n][k] = bf16(w[k][n]); bucket_cur[b] = b*SLAB_F ----------
__global__ void __launch_bounds__(256)
initw_kernel(const float* __restrict__ w, unsigned short* __restrict__ wt,
             int* __restrict__ bucket_cur) {
    if (blockIdx.x == 64) {
        for (int i = threadIdx.x; i < NFB; i += 256)
            bucket_cur[i] = i * SLAB_F;
        return;
    }
    int idx = blockIdx.x * 256 + threadIdx.x;
    int n = idx >> 7, k = idx & 127;
    wt[n * F_DIM + k] = f2bf(w[k * F_DIM + n]);
}

// ---- bin: stage BIN_CHUNK edges, counting-sort by 64-row bucket, flush ---
__global__ void __launch_bounds__(BIN_T)
bin_kernel(const int* __restrict__ rows, const int* __restrict__ cols,
           const float* __restrict__ vals, int* __restrict__ bucket_cur,
           uint2* __restrict__ ebin, int n_edges) {
    __shared__ int lcnt[NFB_PAD];          // counts, then running position
    __shared__ int lbase[NFB_PAD];         // local exclusive prefix
    __shared__ int garr[NFB_PAD];          // reserved global base
    __shared__ int part[BIN_T];            // scan workspace
    __shared__ uint2 srec[BIN_CHUNK];      // bucket-sorted records (32 KB)
    __shared__ unsigned short sb[BIN_CHUNK];

    const int t = threadIdx.x;
    const int base = blockIdx.x * BIN_CHUNK;

    for (int i = t; i < NFB_PAD; i += BIN_T) lcnt[i] = 0;
    __syncthreads();

    unsigned int mykey[BIN_EPT];
    float myval[BIN_EPT];
    bool myok[BIN_EPT];
#pragma unroll
    for (int j = 0; j < BIN_EPT; j++) {
        int e = base + j * BIN_T + t;
        myok[j] = (e < n_edges);
        if (myok[j]) {
            int r = rows[e];
            int c = cols[e];
            myval[j] = vals[e];
            mykey[j] = ((unsigned)r << 16) | (unsigned)c;
            atomicAdd(&lcnt[r >> 6], 1);
        }
    }
    __syncthreads();

    // exclusive scan over NFB buckets: 256 threads x 4 buckets each
    {
        const int b0 = t * 4;
        int s4 = 0;
#pragma unroll
        for (int j = 0; j < 4; j++)
            if (b0 + j < NFB_PAD) s4 += lcnt[b0 + j];
        part[t] = s4;
        __syncthreads();
        for (int d = 1; d < BIN_T; d <<= 1) {
            int u = (t >= d) ? part[t - d] : 0;
            __syncthreads();
            part[t] += u;
            __syncthreads();
        }
        int run = part[t] - s4;   // exclusive prefix of this thread's chunk
#pragma unroll
        for (int j = 0; j < 4; j++) {
            int b = b0 + j;
            if (b < NFB_PAD) {
                lbase[b] = run;
                run += lcnt[b];
            }
        }
    }
    __syncthreads();
    // reserve global slab space; reset lcnt to running placement base
    for (int b = t; b < NFB; b += BIN_T) {
        int c = lcnt[b];
        if (c > 0) garr[b] = atomicAdd(&bucket_cur[b], c);
        lcnt[b] = lbase[b];
    }
    __syncthreads();

#pragma unroll
    for (int j = 0; j < BIN_EPT; j++) {
        if (myok[j]) {
            int b = (int)(mykey[j] >> 22);        // row >> 6
            int p = atomicAdd(&lcnt[b], 1);
            srec[p] = make_uint2(mykey[j], __float_as_uint(myval[j]));
            sb[p] = (unsigned short)b;
        }
    }
    __syncthreads();

    const int m = min(BIN_CHUNK, n_edges - base);
    for (int i = t; i < m; i += BIN_T) {
        int b = sb[i];
        int dst = garr[b] + (i - lbase[b]);
        if (dst < (b + 1) * SLAB_F) ebin[dst] = srec[i];  // overflow guard
    }
}

// ---- GEMM: support_bf16 = bf16(x @ W) via MFMA ---------------------------
__global__ void __launch_bounds__(256)
gemm_mfma_kernel(const float* __restrict__ x, const unsigned short* __restrict__ wt,
                 unsigned short* __restrict__ support) {
    const int tid = threadIdx.x;
    const int wid = tid >> 6;
    const int lane = tid & 63;
    const int l15 = lane & 15;
    const int lhi = lane >> 4;           // 0..3

    const int m0 = (blockIdx.x >> 1) * 16;           // 3125*16 = 50000 exact
    const int n0 = (blockIdx.x & 1) * 64 + wid * 16;

    const float* xrow = x + (size_t)(m0 + l15) * F_DIM + lhi * 8;
    const unsigned short* wrow = wt + (size_t)(n0 + l15) * F_DIM + lhi * 8;

    f32x4 acc = {0.f, 0.f, 0.f, 0.f};
#pragma unroll
    for (int k0 = 0; k0 < F_DIM; k0 += 32) {
        float4 xa = *reinterpret_cast<const float4*>(xrow + k0);
        float4 xb = *reinterpret_cast<const float4*>(xrow + k0 + 4);
        bf16x8 a, b;
        a[0] = (short)f2bf(xa.x); a[1] = (short)f2bf(xa.y);
        a[2] = (short)f2bf(xa.z); a[3] = (short)f2bf(xa.w);
        a[4] = (short)f2bf(xb.x); a[5] = (short)f2bf(xb.y);
        a[6] = (short)f2bf(xb.z); a[7] = (short)f2bf(xb.w);
        b = *reinterpret_cast<const bf16x8*>(wrow + k0);
        acc = __builtin_amdgcn_mfma_f32_16x16x32_bf16(a, b, acc, 0, 0, 0);
    }

    unsigned short* sp = support + (size_t)(m0 + 4 * lhi) * F_DIM + n0 + l15;
#pragma unroll
    for (int i = 0; i < 4; i++)
        sp[(size_t)i * F_DIM] = f2bf(acc[i]);
}

// ---- bspmm: 4 waves/block; wave owns 16 rows + private LDS strip;
//      no atomics, no barriers ---------------------------------------------
__global__ void __launch_bounds__(256)
bspmm_kernel(const unsigned short* __restrict__ support,
             const uint2* __restrict__ ebin, const int* __restrict__ bucket_cur,
             const float* __restrict__ bias, float* __restrict__ out,
             int n_nodes) {
    __shared__ float strip[4][16 * F_DIM];   // 32 KB; strip[w] is wave-private

    const int blk = blockIdx.x;
    const int w0 = blk * 64;
    const int s = blk * SLAB_F;
    const int e = min(bucket_cur[blk], (blk + 1) * SLAB_F);

    const int t = threadIdx.x;
    const int w = t >> 6;
    const int lane = t & 63;
    const unsigned foff = lane * 2u;
    const int wbase = w0 + w * 16;           // first row this wave owns

    float* my = &strip[w][0];
    // zero own strip (same-wave LDS ordering is handled by lgkmcnt)
    float4* my4 = reinterpret_cast<float4*>(my);
    for (int i = lane; i < 16 * F_DIM / 4; i += 64)
        my4[i] = make_float4(0.f, 0.f, 0.f, 0.f);

#define PROC(RR)                                                              \
    {                                                                         \
        int rr = (int)((RR).x >> 16) - wbase;                                 \
        if ((unsigned)rr < 16u) { /* wave-uniform branch */                   \
            float v = __uint_as_float((RR).y);                                \
            unsigned sv = *reinterpret_cast<const unsigned*>(                 \
                support + (size_t)((RR).x & 0xffffu) * F_DIM + foff);         \
            float* p = my + rr * F_DIM + foff;                                \
            p[0] += v * __uint_as_float(sv << 16);                            \
            p[1] += v * __uint_as_float(sv & 0xFFFF0000u);                    \
        }                                                                     \
    }

    int i = s;
#pragma unroll 1
    for (; i + 3 < e; i += 4) {
        uint2 r0 = ebin[i];
        uint2 r1 = ebin[i + 1];
        uint2 r2 = ebin[i + 2];
        uint2 r3 = ebin[i + 3];
        PROC(r0) PROC(r1) PROC(r2) PROC(r3)
    }
#pragma unroll 1
    for (; i < e; i++) {
        uint2 r0 = ebin[i];
        PROC(r0)
    }
#undef PROC

    // epilogue: out[row] = strip[row] + bias (coalesced float2 stores)
    const float2 bb = *reinterpret_cast<const float2*>(bias + foff);
#pragma unroll
    for (int r = 0; r < 16; r++) {
        int row = wbase + r;
        if (row < n_nodes) {
            float2 o;
            o.x = my[r * F_DIM + foff] + bb.x;
            o.y = my[r * F_DIM + foff + 1] + bb.y;
            *reinterpret_cast<float2*>(out + (size_t)row * F_DIM + foff) = o;
        }
    }
}

extern "C" void kernel_launch(void* const* d_in, const int* in_sizes, int n_in,
                              void* d_out, int out_size, void* d_ws, size_t ws_size,
                              hipStream_t stream) {
    const float* x      = (const float*)d_in[0];
    const float* weight = (const float*)d_in[1];
    const float* bias   = (const float*)d_in[2];
    const float* evals  = (const float*)d_in[3];
    const int*   erows  = (const int*)d_in[4];
    const int*   ecols  = (const int*)d_in[5];
    float* out = (float*)d_out;

    const int n_nodes = in_sizes[0] / F_DIM;   // 50000
    const int n_edges = in_sizes[3];           // 625000

    // Workspace layout (~19.3 MB)
    unsigned short* support = (unsigned short*)d_ws;                  // n_nodes*128 bf16
    unsigned short* wt      = support + (size_t)n_nodes * F_DIM;      // 128*128 bf16
    int* bucket_cur = (int*)(wt + F_DIM * F_DIM);                     // NFB
    uintptr_t ep = (uintptr_t)(bucket_cur + NFB);
    ep = (ep + 15) & ~(uintptr_t)15;
    uint2* ebin = (uint2*)ep;                                         // NFB*SLAB_F*8 B

    // 1) wt = bf16(w^T); bucket allocators
    initw_kernel<<<65, 256, 0, stream>>>(weight, wt, bucket_cur);

    // 2) bin edges into 64-row buckets (segment-flushed counting sort)
    int bin_blocks = (n_edges + BIN_CHUNK - 1) / BIN_CHUNK;           // 153
    bin_kernel<<<bin_blocks, BIN_T, 0, stream>>>(erows, ecols, evals,
                                                 bucket_cur, ebin, n_edges);

    // 3) support = bf16(x @ W) via MFMA
    gemm_mfma_kernel<<<(n_nodes / 16) * 2, 256, 0, stream>>>(x, wt, support);

    // 4) windowed pull-spmm: wave-private strips, no atomics
    bspmm_kernel<<<NFB, 256, 0, stream>>>(support, ebin, bucket_cur,
                                          bias, out, n_nodes);
}

// Round 10
// 99.097 us; speedup vs baseline: 5.9880x; 1.9208x over previous
//
#include <hip/hip_runtime.h>
#include <hip/hip_bf16.h>

// GCN layer: out = spmm(adj, x @ W) + bias
// Inputs: x[50000,128] f32, weight[128,128] f32, bias[128] f32,
//         edge_vals[625000] f32, edge_rows[625000] i32, edge_cols[625000] i32
// Output: out[50000,128] f32
//
// Round 10 pipeline (4 dispatches):
//   initw : wt = bf16(w^T); bucket allocators
//   bin   : LDS-staged counting sort of 8-B records into 3125 buckets of
//           16 rows each (segment-flushed writes)
//   gemm  : support = bf16(x @ W) via MFMA
//   bspmm : wave per 16-row bucket; wave reads EXACTLY its own records
//           (no redundant scan, no ownership branch), 8 records in flight,
//           wave-private LDS strip, no atomics, no barriers.
// Round-7/8 lesson: float atomicAdd/unsafeAtomicAdd on __shared__ lowers to
// the flat path (535 us) -> never use float atomics on LDS.

#define F_DIM 128

#define NFB 3125                // buckets: row >> 4 (16 rows each)
#define NFB_PAD 3328            // 256*13, scan coverage
#define SLAB_F 352              // records per bucket (mean 200, +10.7 sigma)

#define BIN_T 256
#define BIN_EPT 16
#define BIN_CHUNK (BIN_T * BIN_EPT)     // 4096 edges per block

typedef short bf16x8 __attribute__((ext_vector_type(8)));
typedef float f32x4 __attribute__((ext_vector_type(4)));

__device__ __forceinline__ unsigned short f2bf(float f) {
    unsigned int u = __float_as_uint(f);
    u += 0x7FFFu + ((u >> 16) & 1u);   // round-to-nearest-even
    return (unsigned short)(u >> 16);
}

// ---- initw: wt[n][k] = bf16(w[k][n]); bucket_cur[b] = b*SLAB_F ----------
__global__ void __launch_bounds__(256)
initw_kernel(const float* __restrict__ w, unsigned short* __restrict__ wt,
             int* __restrict__ bucket_cur) {
    if (blockIdx.x == 64) {
        for (int i = threadIdx.x; i < NFB; i += 256)
            bucket_cur[i] = i * SLAB_F;
        return;
    }
    int idx = blockIdx.x * 256 + threadIdx.x;
    int n = idx >> 7, k = idx & 127;
    wt[n * F_DIM + k] = f2bf(w[k * F_DIM + n]);
}

// ---- bin: stage BIN_CHUNK edges, counting-sort by 16-row bucket, flush ---
// LDS: lcnt 13.3K + lgofs 13.3K + part 1K + srec 32K = ~60 KB
__global__ void __launch_bounds__(BIN_T)
bin_kernel(const int* __restrict__ rows, const int* __restrict__ cols,
           const float* __restrict__ vals, int* __restrict__ bucket_cur,
           uint2* __restrict__ ebin, int n_edges) {
    __shared__ int lcnt[NFB_PAD];     // counts -> running placement pos
    __shared__ int lgofs[NFB_PAD];    // local excl prefix -> (global - local)
    __shared__ int part[BIN_T];       // scan workspace
    __shared__ uint2 srec[BIN_CHUNK]; // bucket-sorted records (32 KB)

    const int t = threadIdx.x;
    const int base = blockIdx.x * BIN_CHUNK;

    for (int i = t; i < NFB_PAD; i += BIN_T) lcnt[i] = 0;
    __syncthreads();

    unsigned int mykey[BIN_EPT];
    float myval[BIN_EPT];
    bool myok[BIN_EPT];
#pragma unroll
    for (int j = 0; j < BIN_EPT; j++) {
        int e = base + j * BIN_T + t;
        myok[j] = (e < n_edges);
        if (myok[j]) {
            int r = rows[e];
            int c = cols[e];
            myval[j] = vals[e];
            mykey[j] = ((unsigned)r << 16) | (unsigned)c;
            atomicAdd(&lcnt[r >> 4], 1);
        }
    }
    __syncthreads();

    // exclusive scan over buckets: 256 threads x 13 buckets each
    {
        const int b0 = t * 13;
        int s13 = 0;
#pragma unroll
        for (int j = 0; j < 13; j++) {
            int b = b0 + j;
            if (b < NFB_PAD) s13 += lcnt[b];
        }
        part[t] = s13;
        __syncthreads();
        for (int d = 1; d < BIN_T; d <<= 1) {
            int u = (t >= d) ? part[t - d] : 0;
            __syncthreads();
            part[t] += u;
            __syncthreads();
        }
        int run = part[t] - s13;   // exclusive prefix of this thread's chunk
#pragma unroll
        for (int j = 0; j < 13; j++) {
            int b = b0 + j;
            if (b < NFB_PAD) {
                lgofs[b] = run;        // local exclusive prefix (for now)
                run += lcnt[b];
            }
        }
    }
    __syncthreads();
    // reserve global slab space; lcnt -> running placement base;
    // lgofs -> (global base - local base)
    for (int b = t; b < NFB; b += BIN_T) {
        int c = lcnt[b];
        int lb = lgofs[b];
        int g = (c > 0) ? atomicAdd(&bucket_cur[b], c) : 0;
        lcnt[b] = lb;
        lgofs[b] = g - lb;
    }
    __syncthreads();

#pragma unroll
    for (int j = 0; j < BIN_EPT; j++) {
        if (myok[j]) {
            int b = (int)(mykey[j] >> 20);        // row >> 4
            int p = atomicAdd(&lcnt[b], 1);
            srec[p] = make_uint2(mykey[j], __float_as_uint(myval[j]));
        }
    }
    __syncthreads();

    const int m = min(BIN_CHUNK, n_edges - base);
    for (int i = t; i < m; i += BIN_T) {
        uint2 rec = srec[i];
        int b = (int)(rec.x >> 20);
        int dst = lgofs[b] + i;
        if (dst < (b + 1) * SLAB_F) ebin[dst] = rec;   // overflow guard
    }
}

// ---- GEMM: support_bf16 = bf16(x @ W) via MFMA ---------------------------
__global__ void __launch_bounds__(256)
gemm_mfma_kernel(const float* __restrict__ x, const unsigned short* __restrict__ wt,
                 unsigned short* __restrict__ support) {
    const int tid = threadIdx.x;
    const int wid = tid >> 6;
    const int lane = tid & 63;
    const int l15 = lane & 15;
    const int lhi = lane >> 4;           // 0..3

    const int m0 = (blockIdx.x >> 1) * 16;           // 3125*16 = 50000 exact
    const int n0 = (blockIdx.x & 1) * 64 + wid * 16;

    const float* xrow = x + (size_t)(m0 + l15) * F_DIM + lhi * 8;
    const unsigned short* wrow = wt + (size_t)(n0 + l15) * F_DIM + lhi * 8;

    f32x4 acc = {0.f, 0.f, 0.f, 0.f};
#pragma unroll
    for (int k0 = 0; k0 < F_DIM; k0 += 32) {
        float4 xa = *reinterpret_cast<const float4*>(xrow + k0);
        float4 xb = *reinterpret_cast<const float4*>(xrow + k0 + 4);
        bf16x8 a, b;
        a[0] = (short)f2bf(xa.x); a[1] = (short)f2bf(xa.y);
        a[2] = (short)f2bf(xa.z); a[3] = (short)f2bf(xa.w);
        a[4] = (short)f2bf(xb.x); a[5] = (short)f2bf(xb.y);
        a[6] = (short)f2bf(xb.z); a[7] = (short)f2bf(xb.w);
        b = *reinterpret_cast<const bf16x8*>(wrow + k0);
        acc = __builtin_amdgcn_mfma_f32_16x16x32_bf16(a, b, acc, 0, 0, 0);
    }

    unsigned short* sp = support + (size_t)(m0 + 4 * lhi) * F_DIM + n0 + l15;
#pragma unroll
    for (int i = 0; i < 4; i++)
        sp[(size_t)i * F_DIM] = f2bf(acc[i]);
}

// ---- bspmm: wave per 16-row bucket; private LDS strip; no atomics --------
__global__ void __launch_bounds__(256)
bspmm_kernel(const unsigned short* __restrict__ support,
             const uint2* __restrict__ ebin, const int* __restrict__ bucket_cur,
             const float* __restrict__ bias, float* __restrict__ out,
             int n_nodes) {
    __shared__ float strip[4][16 * F_DIM];   // 32 KB; strip[w] is wave-private

    const int t = threadIdx.x;
    const int w = t >> 6;
    const int lane = t & 63;
    const unsigned foff = lane * 2u;
    const int bkt = blockIdx.x * 4 + w;

    float* my = &strip[w][0];
    float4* my4 = reinterpret_cast<float4*>(my);
    for (int i = lane; i < 16 * F_DIM / 4; i += 64)
        my4[i] = make_float4(0.f, 0.f, 0.f, 0.f);

    if (bkt >= NFB) return;

    const int w0row = bkt * 16;
    const int s = bkt * SLAB_F;
    const int e = min(bucket_cur[bkt], s + SLAB_F);

// All records in this slab belong to this wave: no branch.
#define PROC(KEY, VAL)                                                        \
    {                                                                         \
        int rr = (int)((KEY) >> 16) - w0row;                                  \
        float v = __uint_as_float(VAL);                                       \
        unsigned sv = *reinterpret_cast<const unsigned*>(                     \
            support + (size_t)((KEY) & 0xffffu) * F_DIM + foff);              \
        float2* p = reinterpret_cast<float2*>(my + rr * F_DIM + foff);        \
        float2 pv = *p;                                                       \
        pv.x += v * __uint_as_float(sv << 16);                                \
        pv.y += v * __uint_as_float(sv & 0xFFFF0000u);                        \
        *p = pv;                                                              \
    }

    int i = s;
#pragma unroll 1
    for (; i + 7 < e; i += 8) {   // 8 records: 4 uint4 loads, 8 gathers in flight
        uint4 a = *reinterpret_cast<const uint4*>(&ebin[i]);
        uint4 b = *reinterpret_cast<const uint4*>(&ebin[i + 2]);
        uint4 c = *reinterpret_cast<const uint4*>(&ebin[i + 4]);
        uint4 d = *reinterpret_cast<const uint4*>(&ebin[i + 6]);
        PROC(a.x, a.y) PROC(a.z, a.w)
        PROC(b.x, b.y) PROC(b.z, b.w)
        PROC(c.x, c.y) PROC(c.z, c.w)
        PROC(d.x, d.y) PROC(d.z, d.w)
    }
#pragma unroll 1
    for (; i < e; i++) {
        uint2 r = ebin[i];
        PROC(r.x, r.y)
    }
#undef PROC

    // epilogue: out[row] = strip[row] + bias (coalesced float2 stores)
    const float2 bb = *reinterpret_cast<const float2*>(bias + foff);
#pragma unroll
    for (int r = 0; r < 16; r++) {
        int row = w0row + r;   // bkt < 3125 -> row < 50000 always
        float2 o;
        o.x = my[r * F_DIM + foff] + bb.x;
        o.y = my[r * F_DIM + foff + 1] + bb.y;
        *reinterpret_cast<float2*>(out + (size_t)row * F_DIM + foff) = o;
    }
}

extern "C" void kernel_launch(void* const* d_in, const int* in_sizes, int n_in,
                              void* d_out, int out_size, void* d_ws, size_t ws_size,
                              hipStream_t stream) {
    const float* x      = (const float*)d_in[0];
    const float* weight = (const float*)d_in[1];
    const float* bias   = (const float*)d_in[2];
    const float* evals  = (const float*)d_in[3];
    const int*   erows  = (const int*)d_in[4];
    const int*   ecols  = (const int*)d_in[5];
    float* out = (float*)d_out;

    const int n_nodes = in_sizes[0] / F_DIM;   // 50000
    const int n_edges = in_sizes[3];           // 625000

    // Workspace layout (~21.6 MB)
    unsigned short* support = (unsigned short*)d_ws;                  // n_nodes*128 bf16
    unsigned short* wt      = support + (size_t)n_nodes * F_DIM;      // 128*128 bf16
    int* bucket_cur = (int*)(wt + F_DIM * F_DIM);                     // NFB
    uintptr_t ep = (uintptr_t)(bucket_cur + NFB);
    ep = (ep + 15) & ~(uintptr_t)15;
    uint2* ebin = (uint2*)ep;                                         // NFB*SLAB_F*8 B

    // 1) wt = bf16(w^T); bucket allocators
    initw_kernel<<<65, 256, 0, stream>>>(weight, wt, bucket_cur);

    // 2) bin edges into 16-row buckets (segment-flushed counting sort)
    int bin_blocks = (n_edges + BIN_CHUNK - 1) / BIN_CHUNK;           // 153
    bin_kernel<<<bin_blocks, BIN_T, 0, stream>>>(erows, ecols, evals,
                                                 bucket_cur, ebin, n_edges);

    // 3) support = bf16(x @ W) via MFMA
    gemm_mfma_kernel<<<(n_nodes / 16) * 2, 256, 0, stream>>>(x, wt, support);

    // 4) wave-per-bucket pull-spmm: private strips, no atomics, no waste
    int spmm_blocks = (NFB + 3) / 4;                                  // 782
    bspmm_kernel<<<spmm_blocks, 256, 0, stream>>>(support, ebin, bucket_cur,
                                                  bias, out, n_nodes);
}

// Round 11
// 86.840 us; speedup vs baseline: 6.8331x; 1.1411x over previous
//
#include <hip/hip_runtime.h>
#include <hip/hip_bf16.h>

// GCN layer: out = spmm(adj, x @ W) + bias
// Inputs: x[50000,128] f32, weight[128,128] f32, bias[128] f32,
//         edge_vals[625000] f32, edge_rows[625000] i32, edge_cols[625000] i32
// Output: out[50000,128] f32
//
// Round 11 pipeline (4 dispatches):
//   initw : wt = bf16(w^T); bucket allocators            [unchanged]
//   bin   : counting sort of 8-B records into 3125 16-row buckets [unchanged]
//   gemm  : support = bf16(x @ W) via MFMA, single pass over x (16x128/block)
//   bspmm : wave per bucket; REGISTER accumulators ax/ay[16] updated via
//           wave-uniform 16-case switch (r10's LDS RMW removed entirely);
//           8 gathers in flight, next-record prefetch; no LDS, no atomics.
// Lessons kept: float atomics on __shared__ lower to flat path (535us, r7/8);
// random 8-B global scatter = 8x write amplification (r5).

#define F_DIM 128

#define NFB 3125                // buckets: row >> 4 (16 rows each)
#define NFB_PAD 3328            // 256*13, scan coverage
#define SLAB_F 352              // records per bucket (mean 200, +10.7 sigma)

#define BIN_T 256
#define BIN_EPT 16
#define BIN_CHUNK (BIN_T * BIN_EPT)     // 4096 edges per block

typedef short bf16x8 __attribute__((ext_vector_type(8)));
typedef float f32x4 __attribute__((ext_vector_type(4)));

__device__ __forceinline__ unsigned short f2bf(float f) {
    unsigned int u = __float_as_uint(f);
    u += 0x7FFFu + ((u >> 16) & 1u);   // round-to-nearest-even
    return (unsigned short)(u >> 16);
}

// ---- initw: wt[n][k] = bf16(w[k][n]); bucket_cur[b] = b*SLAB_F ----------
__global__ void __launch_bounds__(256)
initw_kernel(const float* __restrict__ w, unsigned short* __restrict__ wt,
             int* __restrict__ bucket_cur) {
    if (blockIdx.x == 64) {
        for (int i = threadIdx.x; i < NFB; i += 256)
            bucket_cur[i] = i * SLAB_F;
        return;
    }
    int idx = blockIdx.x * 256 + threadIdx.x;
    int n = idx >> 7, k = idx & 127;
    wt[n * F_DIM + k] = f2bf(w[k * F_DIM + n]);
}

// ---- bin: stage BIN_CHUNK edges, counting-sort by 16-row bucket, flush ---
__global__ void __launch_bounds__(BIN_T)
bin_kernel(const int* __restrict__ rows, const int* __restrict__ cols,
           const float* __restrict__ vals, int* __restrict__ bucket_cur,
           uint2* __restrict__ ebin, int n_edges) {
    __shared__ int lcnt[NFB_PAD];     // counts -> running placement pos
    __shared__ int lgofs[NFB_PAD];    // local excl prefix -> (global - local)
    __shared__ int part[BIN_T];       // scan workspace
    __shared__ uint2 srec[BIN_CHUNK]; // bucket-sorted records (32 KB)

    const int t = threadIdx.x;
    const int base = blockIdx.x * BIN_CHUNK;

    for (int i = t; i < NFB_PAD; i += BIN_T) lcnt[i] = 0;
    __syncthreads();

    unsigned int mykey[BIN_EPT];
    float myval[BIN_EPT];
    bool myok[BIN_EPT];
#pragma unroll
    for (int j = 0; j < BIN_EPT; j++) {
        int e = base + j * BIN_T + t;
        myok[j] = (e < n_edges);
        if (myok[j]) {
            int r = rows[e];
            int c = cols[e];
            myval[j] = vals[e];
            mykey[j] = ((unsigned)r << 16) | (unsigned)c;
            atomicAdd(&lcnt[r >> 4], 1);
        }
    }
    __syncthreads();

    // exclusive scan over buckets: 256 threads x 13 buckets each
    {
        const int b0 = t * 13;
        int s13 = 0;
#pragma unroll
        for (int j = 0; j < 13; j++) {
            int b = b0 + j;
            if (b < NFB_PAD) s13 += lcnt[b];
        }
        part[t] = s13;
        __syncthreads();
        for (int d = 1; d < BIN_T; d <<= 1) {
            int u = (t >= d) ? part[t - d] : 0;
            __syncthreads();
            part[t] += u;
            __syncthreads();
        }
        int run = part[t] - s13;   // exclusive prefix of this thread's chunk
#pragma unroll
        for (int j = 0; j < 13; j++) {
            int b = b0 + j;
            if (b < NFB_PAD) {
                lgofs[b] = run;        // local exclusive prefix (for now)
                run += lcnt[b];
            }
        }
    }
    __syncthreads();
    // reserve global slab space; lcnt -> running placement base;
    // lgofs -> (global base - local base)
    for (int b = t; b < NFB; b += BIN_T) {
        int c = lcnt[b];
        int lb = lgofs[b];
        int g = (c > 0) ? atomicAdd(&bucket_cur[b], c) : 0;
        lcnt[b] = lb;
        lgofs[b] = g - lb;
    }
    __syncthreads();

#pragma unroll
    for (int j = 0; j < BIN_EPT; j++) {
        if (myok[j]) {
            int b = (int)(mykey[j] >> 20);        // row >> 4
            int p = atomicAdd(&lcnt[b], 1);
            srec[p] = make_uint2(mykey[j], __float_as_uint(myval[j]));
        }
    }
    __syncthreads();

    const int m = min(BIN_CHUNK, n_edges - base);
    for (int i = t; i < m; i += BIN_T) {
        uint2 rec = srec[i];
        int b = (int)(rec.x >> 20);
        int dst = lgofs[b] + i;
        if (dst < (b + 1) * SLAB_F) ebin[dst] = rec;   // overflow guard
    }
}

// ---- GEMM: support_bf16 = bf16(x @ W), single pass over x ----------------
// Block = 256 = 4 waves; block tile 16 rows x 128 cols; wave: 16x32
// (two 16x16 n-tiles sharing one A-frag). x fetched once (25.6 MB).
__global__ void __launch_bounds__(256)
gemm_mfma_kernel(const float* __restrict__ x, const unsigned short* __restrict__ wt,
                 unsigned short* __restrict__ support) {
    const int tid = threadIdx.x;
    const int wid = tid >> 6;
    const int lane = tid & 63;
    const int l15 = lane & 15;
    const int lhi = lane >> 4;           // 0..3

    const int m0 = blockIdx.x * 16;      // 3125 blocks
    const int n0 = wid * 32;

    const float* xrow = x + (size_t)(m0 + l15) * F_DIM + lhi * 8;
    const unsigned short* wrow0 = wt + (size_t)(n0 + l15) * F_DIM + lhi * 8;
    const unsigned short* wrow1 = wrow0 + 16 * F_DIM;

    f32x4 acc0 = {0.f, 0.f, 0.f, 0.f};
    f32x4 acc1 = {0.f, 0.f, 0.f, 0.f};
#pragma unroll
    for (int k0 = 0; k0 < F_DIM; k0 += 32) {
        float4 xa = *reinterpret_cast<const float4*>(xrow + k0);
        float4 xb = *reinterpret_cast<const float4*>(xrow + k0 + 4);
        bf16x8 a, b0, b1;
        a[0] = (short)f2bf(xa.x); a[1] = (short)f2bf(xa.y);
        a[2] = (short)f2bf(xa.z); a[3] = (short)f2bf(xa.w);
        a[4] = (short)f2bf(xb.x); a[5] = (short)f2bf(xb.y);
        a[6] = (short)f2bf(xb.z); a[7] = (short)f2bf(xb.w);
        b0 = *reinterpret_cast<const bf16x8*>(wrow0 + k0);
        b1 = *reinterpret_cast<const bf16x8*>(wrow1 + k0);
        acc0 = __builtin_amdgcn_mfma_f32_16x16x32_bf16(a, b0, acc0, 0, 0, 0);
        acc1 = __builtin_amdgcn_mfma_f32_16x16x32_bf16(a, b1, acc1, 0, 0, 0);
    }

    // D: row = m0 + 4*lhi + i, cols n0 + l15 and n0 + 16 + l15
    unsigned short* sp = support + (size_t)(m0 + 4 * lhi) * F_DIM + n0 + l15;
#pragma unroll
    for (int i = 0; i < 4; i++) {
        sp[(size_t)i * F_DIM]      = f2bf(acc0[i]);
        sp[(size_t)i * F_DIM + 16] = f2bf(acc1[i]);
    }
}

// ---- bspmm: wave per 16-row bucket; register acc + uniform switch --------
#define UPD(KEY, VAL, SV)                                                     \
    {                                                                         \
        float v = __uint_as_float(VAL);                                       \
        float cx = v * __uint_as_float((SV) << 16);                           \
        float cy = v * __uint_as_float((SV) & 0xFFFF0000u);                   \
        switch (((KEY) >> 16) & 15u) { /* wave-uniform */                     \
        case 0:  ax[0] += cx;  ay[0] += cy;  break;                           \
        case 1:  ax[1] += cx;  ay[1] += cy;  break;                           \
        case 2:  ax[2] += cx;  ay[2] += cy;  break;                           \
        case 3:  ax[3] += cx;  ay[3] += cy;  break;                           \
        case 4:  ax[4] += cx;  ay[4] += cy;  break;                           \
        case 5:  ax[5] += cx;  ay[5] += cy;  break;                           \
        case 6:  ax[6] += cx;  ay[6] += cy;  break;                           \
        case 7:  ax[7] += cx;  ay[7] += cy;  break;                           \
        case 8:  ax[8] += cx;  ay[8] += cy;  break;                           \
        case 9:  ax[9] += cx;  ay[9] += cy;  break;                           \
        case 10: ax[10] += cx; ay[10] += cy; break;                           \
        case 11: ax[11] += cx; ay[11] += cy; break;                           \
        case 12: ax[12] += cx; ay[12] += cy; break;                           \
        case 13: ax[13] += cx; ay[13] += cy; break;                           \
        case 14: ax[14] += cx; ay[14] += cy; break;                           \
        case 15: ax[15] += cx; ay[15] += cy; break;                           \
        }                                                                     \
    }

__global__ void __launch_bounds__(64)
bspmm_kernel(const unsigned short* __restrict__ support,
             const uint2* __restrict__ ebin, const int* __restrict__ bucket_cur,
             const float* __restrict__ bias, float* __restrict__ out) {
    const int bkt = blockIdx.x;          // one wave per bucket
    const int lane = threadIdx.x;
    const unsigned foff = lane * 2u;

    const int s = bkt * SLAB_F;
    const int e = min(bucket_cur[bkt], s + SLAB_F);

    float ax[16], ay[16];
#pragma unroll
    for (int r = 0; r < 16; r++) { ax[r] = 0.f; ay[r] = 0.f; }

#define GATHER(K) (*reinterpret_cast<const unsigned*>(                        \
        support + (size_t)((K) & 0xffffu) * F_DIM + foff))

    int i = s;
    if (i + 7 < e) {
        uint4 ra = *reinterpret_cast<const uint4*>(&ebin[i]);
        uint4 rb = *reinterpret_cast<const uint4*>(&ebin[i + 2]);
        uint4 rc = *reinterpret_cast<const uint4*>(&ebin[i + 4]);
        uint4 rd = *reinterpret_cast<const uint4*>(&ebin[i + 6]);
#pragma unroll 1
        while (true) {
            // 8 independent gathers in flight
            unsigned s0 = GATHER(ra.x), s1 = GATHER(ra.z);
            unsigned s2 = GATHER(rb.x), s3 = GATHER(rb.z);
            unsigned s4 = GATHER(rc.x), s5 = GATHER(rc.z);
            unsigned s6 = GATHER(rd.x), s7 = GATHER(rd.z);
            const int inext = i + 8;
            const bool more = (inext + 7 < e);
            uint4 na, nb, nc, nd;
            if (more) {                     // prefetch next records
                na = *reinterpret_cast<const uint4*>(&ebin[inext]);
                nb = *reinterpret_cast<const uint4*>(&ebin[inext + 2]);
                nc = *reinterpret_cast<const uint4*>(&ebin[inext + 4]);
                nd = *reinterpret_cast<const uint4*>(&ebin[inext + 6]);
            }
            UPD(ra.x, ra.y, s0) UPD(ra.z, ra.w, s1)
            UPD(rb.x, rb.y, s2) UPD(rb.z, rb.w, s3)
            UPD(rc.x, rc.y, s4) UPD(rc.z, rc.w, s5)
            UPD(rd.x, rd.y, s6) UPD(rd.z, rd.w, s7)
            i = inext;
            if (!more) break;
            ra = na; rb = nb; rc = nc; rd = nd;
        }
    }
#pragma unroll 1
    for (; i < e; i++) {
        uint2 r = ebin[i];
        unsigned sv = GATHER(r.x);
        UPD(r.x, r.y, sv)
    }
#undef GATHER

    // epilogue: out[bkt*16 + r] = acc[r] + bias (coalesced float2 stores)
    const float2 bb = *reinterpret_cast<const float2*>(bias + foff);
    float* op = out + (size_t)bkt * 16 * F_DIM + foff;
#pragma unroll
    for (int r = 0; r < 16; r++) {
        float2 o = make_float2(ax[r] + bb.x, ay[r] + bb.y);
        *reinterpret_cast<float2*>(op + (size_t)r * F_DIM) = o;
    }
}
#undef UPD

extern "C" void kernel_launch(void* const* d_in, const int* in_sizes, int n_in,
                              void* d_out, int out_size, void* d_ws, size_t ws_size,
                              hipStream_t stream) {
    const float* x      = (const float*)d_in[0];
    const float* weight = (const float*)d_in[1];
    const float* bias   = (const float*)d_in[2];
    const float* evals  = (const float*)d_in[3];
    const int*   erows  = (const int*)d_in[4];
    const int*   ecols  = (const int*)d_in[5];
    float* out = (float*)d_out;

    const int n_nodes = in_sizes[0] / F_DIM;   // 50000
    const int n_edges = in_sizes[3];           // 625000

    // Workspace layout (~21.6 MB)
    unsigned short* support = (unsigned short*)d_ws;                  // n_nodes*128 bf16
    unsigned short* wt      = support + (size_t)n_nodes * F_DIM;      // 128*128 bf16
    int* bucket_cur = (int*)(wt + F_DIM * F_DIM);                     // NFB
    uintptr_t ep = (uintptr_t)(bucket_cur + NFB);
    ep = (ep + 15) & ~(uintptr_t)15;
    uint2* ebin = (uint2*)ep;                                         // NFB*SLAB_F*8 B

    // 1) wt = bf16(w^T); bucket allocators
    initw_kernel<<<65, 256, 0, stream>>>(weight, wt, bucket_cur);

    // 2) bin edges into 16-row buckets (segment-flushed counting sort)
    int bin_blocks = (n_edges + BIN_CHUNK - 1) / BIN_CHUNK;           // 153
    bin_kernel<<<bin_blocks, BIN_T, 0, stream>>>(erows, ecols, evals,
                                                 bucket_cur, ebin, n_edges);

    // 3) support = bf16(x @ W) via MFMA (single pass over x)
    gemm_mfma_kernel<<<n_nodes / 16, 256, 0, stream>>>(x, wt, support);

    // 4) wave-per-bucket pull-spmm: register acc, no LDS, no atomics
    bspmm_kernel<<<NFB, 64, 0, stream>>>(support, ebin, bucket_cur, bias, out);
}